// Round 15
// baseline (394.090 us; speedup 1.0000x reference)
//
#include <hip/hip_runtime.h>
#include <hip/hip_bf16.h>
#include <math.h>

#define NG 4
#define NN 50000
#define NE 800000
#define DD 64
#define CAP 64
#define NT 64             // nodes per block tile
#define NTILE 391         // tiles per (graph, half)
#define NTG (2 * NTILE)   // tiles (regions) per graph = 782
#define HCAP 768          // region capacity PER SRC-HALF
#define CPAD 16           // ints per region counter (one 64B line each)
#define PBLK 128          // partition blocks per slot
#define CHUNK (NE / PBLK)
#define LBINS 392
#define BCAP2 10

typedef __attribute__((ext_vector_type(8))) short short8;
typedef __attribute__((ext_vector_type(4))) float float4v;

__device__ __forceinline__ unsigned short f2b(float f) {
    union { __hip_bfloat16 h; unsigned short u; } cv;
    cv.h = __float2bfloat16(f);
    return cv.u;
}
__device__ __forceinline__ float b2f(unsigned short u) {
    union { unsigned short u; __hip_bfloat16 h; } cv;
    cv.u = u;
    return __bfloat162float(cv.h);
}

// ---- init: detect int64 (bit0) + verify MFMA layout (bit1), one block ------
__global__ void init_kernel(const int* __restrict__ ei, int* __restrict__ flags) {
    __shared__ alignas(16) unsigned short A[16 * 32];
    __shared__ unsigned short B[32 * 16];
    int t = threadIdx.x;
    int any_nonzero = 0;
    for (int i = t; i < 128; i += 64) any_nonzero |= ei[2 * i + 1];
    unsigned long long nz = __ballot(any_nonzero != 0);
    int is64 = (nz == 0ULL) ? 1 : 0;
    for (int i = t; i < 512; i += 64) {
        int r = i >> 5, k = i & 31;
        A[i] = f2b((float)(((r * 5 + k * 3) & 31) - 15));
        int kk = i >> 4, c = i & 15;
        B[i] = f2b((float)(((kk * 7 + c * 11) & 31) - 15));
    }
    __syncthreads();
    short8 a = *(const short8*)&A[(t & 15) * 32 + (t >> 4) * 8];
    int c = t & 15, kb = (t >> 4) * 8;
    short8 b;
    for (int j = 0; j < 8; ++j) b[j] = (short)B[(kb + j) * 16 + c];
    float4v acc = {0.f, 0.f, 0.f, 0.f};
    acc = __builtin_amdgcn_mfma_f32_16x16x32_bf16(a, b, acc, 0, 0, 0);
    int ok = 1;
    for (int reg = 0; reg < 4; ++reg) {
        int row = (t >> 4) * 4 + reg;
        float ref = 0.f;
        for (int k = 0; k < 32; ++k)
            ref += (float)(((row * 5 + k * 3) & 31) - 15) *
                   (float)(((k * 7 + c * 11) & 31) - 15);
        if (acc[reg] != ref) ok = 0;
    }
    unsigned long long vote = __ballot(ok);
    if (t == 0) flags[0] = is64 | ((vote == ~0ULL) ? 2 : 0);
}

// nt (streaming) edge-index load
__device__ __forceinline__ int nt_idx(const int* __restrict__ ei, long pos, int is64) {
    return is64 ? __builtin_nontemporal_load(ei + 2 * pos)
                : __builtin_nontemporal_load(ei + pos);
}

// ---- partition: per (region, src-half) lists via LDS-staged aggregation ----
__global__ void partition_kernel(const int* __restrict__ ei, const int* __restrict__ flags,
                                 int* __restrict__ bcnt, unsigned int* __restrict__ part) {
    __shared__ int lcnt[LBINS * 2];
    __shared__ int basev[LBINS * 2];
    __shared__ unsigned int lbuf[LBINS * 2 * BCAP2];

    int is64 = flags[0] & 1;
    int s = blockIdx.x & 7;
    int g = s >> 1;
    int lo = (s & 1) * (NN / 2), hi = lo + (NN / 2);
    int rbase0 = lo >> 6;
    int bsl = blockIdx.x >> 3;
    int e0 = bsl * CHUNK, e1 = e0 + CHUNK;
    long ebase = (long)g * 2 * NE;

    for (int i = threadIdx.x; i < LBINS * 2; i += 256) lcnt[i] = 0;
    __syncthreads();

    for (int e = e0 + threadIdx.x; e < e1; e += 256) {
        int d = nt_idx(ei, ebase + NE + e, is64);
        int sc = nt_idx(ei, ebase + e, is64);
        if (d >= lo && d < hi) {
            int hf = (sc >= NN / 2) ? 1 : 0;
            int lb = ((d >> 6) - rbase0) * 2 + hf;
            unsigned int pk = ((unsigned int)d << 16) | (unsigned int)(sc & 0xffff);
            int pos = atomicAdd(&lcnt[lb], 1);
            if (pos < BCAP2) {
                lbuf[lb * BCAP2 + pos] = pk;
            } else {
                int pidx = (g * NTG + (d >> 6)) * 2 + hf;
                int gp = atomicAdd(&bcnt[pidx * CPAD], 1);
                if (gp < HCAP) part[(long)pidx * HCAP + gp] = pk;
            }
        }
    }
    __syncthreads();

    for (int r = threadIdx.x; r < LBINS * 2; r += 256) {
        int c = lcnt[r]; c = c < BCAP2 ? c : BCAP2;
        int pidx = (g * NTG + rbase0 + (r >> 1)) * 2 + (r & 1);
        basev[r] = c ? atomicAdd(&bcnt[pidx * CPAD], c) : 0;
    }
    __syncthreads();

    int w = threadIdx.x >> 6, hw = (threadIdx.x >> 5) & 1, l32 = threadIdx.x & 31;
    for (int r = w * 2 + hw; r < LBINS * 2; r += 8) {
        int c = lcnt[r]; c = c < BCAP2 ? c : BCAP2;
        int b = basev[r];
        int pidx = (g * NTG + rbase0 + (r >> 1)) * 2 + (r & 1);
        if (l32 < c && b + l32 < HCAP)
            part[(long)pidx * HCAP + b + l32] = lbuf[r * BCAP2 + l32];
    }
}

// ---- convert x f32 -> bf16 -------------------------------------------------
__global__ void convert_kernel(const float* __restrict__ x, unsigned short* __restrict__ xb) {
    long total = (long)NG * NN * DD / 4;
    long stride = (long)gridDim.x * blockDim.x;
    const float4* src = (const float4*)x;
    unsigned long long* dst = (unsigned long long*)xb;
    for (long i = (long)blockIdx.x * blockDim.x + threadIdx.x; i < total; i += stride) {
        float4 v = src[i];
        unsigned long long p = (unsigned long long)f2b(v.x)
                             | ((unsigned long long)f2b(v.y) << 16)
                             | ((unsigned long long)f2b(v.z) << 32)
                             | ((unsigned long long)f2b(v.w) << 48);
        dst[i] = p;
    }
}

// ---- wconv: precompute bf16-swizzled W^T for both layers (once) ------------
__global__ void wconv_kernel(const float* __restrict__ Wl1, const float* __restrict__ Wr1,
                             const float* __restrict__ Wl2, const float* __restrict__ Wr2,
                             unsigned short* __restrict__ wsw) {
    int g = blockIdx.x & 3, layer = blockIdx.x >> 2;
    const float* Wl = layer ? Wl2 : Wl1;
    const float* Wr = layer ? Wr2 : Wr1;
    for (int i = threadIdx.x; i < 2 * DD * DD; i += 256) {
        int m = i >> 12, rem = i & 4095, k = rem >> 6, col = rem & 63;
        float wv = (m == 0 ? Wl : Wr)[(long)g * DD * DD + rem];
        wsw[(((long)layer * NG + g) * 2 + m) * DD * DD + col * DD + (k ^ ((col & 7) << 3))]
            = f2b(wv);
    }
}

// ---- merged sage: bin both halves, two-pass src-half-coherent gather, MFMA --
// ROUND-15: combines r14's L2-residency (src-half phased gather; per-XCD
// working set 3.2MB < 4MB L2) with r13's occupancy (8 blocks/CU, 32 waves) —
// the untested quadrant. Partials stay in LDS (bf16 pbuf, 8KB) so no HBM
// round-trip; W frags from global (L2-hot). Grid = 2048 = one dispatch wave,
// so all blocks enter pass A/B roughly in phase (coherence across blocks).
template <int LAYER>  // 0: out = h (bf16), 1: out = d_out (f32)
__launch_bounds__(256, 8)
__global__ void sage_mfma_kernel(const unsigned short* __restrict__ xin,
                                 const int* __restrict__ bcnt,
                                 const unsigned int* __restrict__ part,
                                 const unsigned short* __restrict__ wsw,
                                 const float* __restrict__ bias, void* __restrict__ outp,
                                 const int* __restrict__ flags) {
    if (!(flags[0] & 2)) return;
    __shared__ alignas(16) unsigned short bk[NT * DD];    // bucket, then means (8KB)
    __shared__ alignas(16) unsigned short pbuf[NT * DD];  // bf16 half-0 partials (8KB)
    __shared__ int cnt_lds[NT];
    __shared__ int cnt0_lds[NT];

    int s = blockIdx.x & 7;
    int bsl = blockIdx.x >> 3, nbsl = gridDim.x >> 3;
    int g = s >> 1;
    long gn0 = (long)g * NN;
    const unsigned short* wt = wsw + ((long)LAYER * NG + g) * 2 * DD * DD;
    int lane = threadIdx.x & 63, w = threadIdx.x >> 6;
    int grp = lane >> 4, fq = lane & 15;
    const char* xg = (const char*)xin + (gn0 << 7);

    for (int tb = bsl; tb < NTILE; tb += nbsl) {
        int tile = (s & 1) * NTILE + tb;
        int base = tile * NT;
        if (tb != bsl) __syncthreads();
        if (threadIdx.x < NT) cnt_lds[threadIdx.x] = 0;
        __syncthreads();

        int pidx = (g * NTG + tile) * 2;
        {   // bin half-0
            int rc = bcnt[pidx * CPAD]; rc = rc < HCAP ? rc : HCAP;
            const unsigned int* reg = part + (long)pidx * HCAP;
            for (int i = threadIdx.x; i < rc; i += 256) {
                unsigned int p = __builtin_nontemporal_load(reg + i);
                int dl = (p >> 16) & 63;
                int pos = atomicAdd(&cnt_lds[dl], 1);
                if (pos < CAP) bk[dl * DD + pos] = (unsigned short)(p & 0xffffu);
            }
        }
        __syncthreads();
        if (threadIdx.x < NT) cnt0_lds[threadIdx.x] = cnt_lds[threadIdx.x];
        __syncthreads();
        {   // bin half-1 (append after half-0)
            int rc = bcnt[(pidx + 1) * CPAD]; rc = rc < HCAP ? rc : HCAP;
            const unsigned int* reg = part + (long)(pidx + 1) * HCAP;
            for (int i = threadIdx.x; i < rc; i += 256) {
                unsigned int p = __builtin_nontemporal_load(reg + i);
                int dl = (p >> 16) & 63;
                int pos = atomicAdd(&cnt_lds[dl], 1);
                if (pos < CAP) bk[dl * DD + pos] = (unsigned short)(p & 0xffffu);
            }
        }
        __syncthreads();

        // ---- PASS A: src half-0 for all rows -> bf16 partial sums in pbuf ----
#pragma unroll 1
        for (int j = 0; j < 8; ++j) {
            int rA = w * 16 + j, rB = rA + 8;
            int c0A = cnt0_lds[rA]; c0A = c0A < CAP ? c0A : CAP; if (base + rA >= NN) c0A = 0;
            int c0B = cnt0_lds[rB]; c0B = c0B < CAP ? c0B : CAP; if (base + rB >= NN) c0B = 0;
            int msA = (int)bk[rA * DD + lane];
            int msB = (int)bk[rB * DD + lane];
            float a0 = 0.f, a1 = 0.f, a2 = 0.f, a3 = 0.f;
            float b0 = 0.f, b1 = 0.f, b2 = 0.f, b3 = 0.f;
            int numax = c0A > c0B ? c0A : c0B;
#pragma unroll 2
            for (int e = 0; e < numax; e += 4) {
                int ei = e + grp;
                bool vA = ei < c0A, vB = ei < c0B;
                int sA = __shfl(msA, vA ? ei : 0);
                int sB = __shfl(msB, vB ? ei : 0);
                sA = sA < NN - 1 ? sA : NN - 1;
                sB = sB < NN - 1 ? sB : NN - 1;
                unsigned long long va =
                    *(const unsigned long long*)(xg + ((long)sA << 7) + (fq << 3));
                unsigned long long vb =
                    *(const unsigned long long*)(xg + ((long)sB << 7) + (fq << 3));
                unsigned int ua0 = (unsigned int)va, ua1 = (unsigned int)(va >> 32);
                unsigned int ub0 = (unsigned int)vb, ub1 = (unsigned int)(vb >> 32);
                if (!vA) { ua0 = 0u; ua1 = 0u; }
                if (!vB) { ub0 = 0u; ub1 = 0u; }
                a0 += __uint_as_float(ua0 << 16);
                a1 += __uint_as_float(ua0 & 0xffff0000u);
                a2 += __uint_as_float(ua1 << 16);
                a3 += __uint_as_float(ua1 & 0xffff0000u);
                b0 += __uint_as_float(ub0 << 16);
                b1 += __uint_as_float(ub0 & 0xffff0000u);
                b2 += __uint_as_float(ub1 << 16);
                b3 += __uint_as_float(ub1 & 0xffff0000u);
            }
            a0 += __shfl_xor(a0, 16); a0 += __shfl_xor(a0, 32);
            a1 += __shfl_xor(a1, 16); a1 += __shfl_xor(a1, 32);
            a2 += __shfl_xor(a2, 16); a2 += __shfl_xor(a2, 32);
            a3 += __shfl_xor(a3, 16); a3 += __shfl_xor(a3, 32);
            b0 += __shfl_xor(b0, 16); b0 += __shfl_xor(b0, 32);
            b1 += __shfl_xor(b1, 16); b1 += __shfl_xor(b1, 32);
            b2 += __shfl_xor(b2, 16); b2 += __shfl_xor(b2, 32);
            b3 += __shfl_xor(b3, 16); b3 += __shfl_xor(b3, 32);
            unsigned long long pA =
                (unsigned long long)((unsigned int)f2b(a0) | ((unsigned int)f2b(a1) << 16))
                | ((unsigned long long)((unsigned int)f2b(a2) | ((unsigned int)f2b(a3) << 16)) << 32);
            unsigned long long pB =
                (unsigned long long)((unsigned int)f2b(b0) | ((unsigned int)f2b(b1) << 16))
                | ((unsigned long long)((unsigned int)f2b(b2) | ((unsigned int)f2b(b3) << 16)) << 32);
            if (grp == 0)      *(unsigned long long*)&pbuf[rA * DD + (fq << 2)] = pA;
            else if (grp == 1) *(unsigned long long*)&pbuf[rB * DD + (fq << 2)] = pB;
        }
        // no barrier: pbuf written/read by the same thread; bk rows own-wave

        // ---- PASS B: src half-1 + partial -> means (swizzled) in bk ----
#pragma unroll 1
        for (int j = 0; j < 8; ++j) {
            int rA = w * 16 + j, rB = rA + 8;
            int ctA = cnt_lds[rA], ctB = cnt_lds[rB];
            int nuA = ctA < CAP ? ctA : CAP; if (base + rA >= NN) nuA = 0;
            int nuB = ctB < CAP ? ctB : CAP; if (base + rB >= NN) nuB = 0;
            int c0A = cnt0_lds[rA]; if (base + rA >= NN) c0A = 0;
            int c0B = cnt0_lds[rB]; if (base + rB >= NN) c0B = 0;
            int kA = nuA - c0A; kA = kA > 0 ? kA : 0;
            int kB = nuB - c0B; kB = kB > 0 ? kB : 0;
            int msA = (int)bk[rA * DD + lane];
            int msB = (int)bk[rB * DD + lane];
            float a0 = 0.f, a1 = 0.f, a2 = 0.f, a3 = 0.f;
            float b0 = 0.f, b1 = 0.f, b2 = 0.f, b3 = 0.f;
            int kmax = kA > kB ? kA : kB;
#pragma unroll 2
            for (int k = 0; k < kmax; k += 4) {
                int eA = c0A + k + grp, eB = c0B + k + grp;
                bool vA = (k + grp) < kA, vB = (k + grp) < kB;
                int sA = __shfl(msA, vA ? eA : 0);
                int sB = __shfl(msB, vB ? eB : 0);
                sA = sA < NN - 1 ? sA : NN - 1;
                sB = sB < NN - 1 ? sB : NN - 1;
                unsigned long long va =
                    *(const unsigned long long*)(xg + ((long)sA << 7) + (fq << 3));
                unsigned long long vb =
                    *(const unsigned long long*)(xg + ((long)sB << 7) + (fq << 3));
                unsigned int ua0 = (unsigned int)va, ua1 = (unsigned int)(va >> 32);
                unsigned int ub0 = (unsigned int)vb, ub1 = (unsigned int)(vb >> 32);
                if (!vA) { ua0 = 0u; ua1 = 0u; }
                if (!vB) { ub0 = 0u; ub1 = 0u; }
                a0 += __uint_as_float(ua0 << 16);
                a1 += __uint_as_float(ua0 & 0xffff0000u);
                a2 += __uint_as_float(ua1 << 16);
                a3 += __uint_as_float(ua1 & 0xffff0000u);
                b0 += __uint_as_float(ub0 << 16);
                b1 += __uint_as_float(ub0 & 0xffff0000u);
                b2 += __uint_as_float(ub1 << 16);
                b3 += __uint_as_float(ub1 & 0xffff0000u);
            }
            a0 += __shfl_xor(a0, 16); a0 += __shfl_xor(a0, 32);
            a1 += __shfl_xor(a1, 16); a1 += __shfl_xor(a1, 32);
            a2 += __shfl_xor(a2, 16); a2 += __shfl_xor(a2, 32);
            a3 += __shfl_xor(a3, 16); a3 += __shfl_xor(a3, 32);
            b0 += __shfl_xor(b0, 16); b0 += __shfl_xor(b0, 32);
            b1 += __shfl_xor(b1, 16); b1 += __shfl_xor(b1, 32);
            b2 += __shfl_xor(b2, 16); b2 += __shfl_xor(b2, 32);
            b3 += __shfl_xor(b3, 16); b3 += __shfl_xor(b3, 32);
            if (grp == 0) {
                unsigned long long q = *(const unsigned long long*)&pbuf[rA * DD + (fq << 2)];
                unsigned int q0 = (unsigned int)q, q1 = (unsigned int)(q >> 32);
                a0 += __uint_as_float(q0 << 16);
                a1 += __uint_as_float(q0 & 0xffff0000u);
                a2 += __uint_as_float(q1 << 16);
                a3 += __uint_as_float(q1 & 0xffff0000u);
                float inv = 1.f / fmaxf((float)ctA, 1.f);
                a0 *= inv; a1 *= inv; a2 *= inv; a3 *= inv;
                unsigned long long pA =
                    (unsigned long long)((unsigned int)f2b(a0) | ((unsigned int)f2b(a1) << 16))
                    | ((unsigned long long)((unsigned int)f2b(a2) | ((unsigned int)f2b(a3) << 16)) << 32);
                int swz = (fq * 4) ^ ((rA & 7) << 3);
                *(unsigned long long*)&bk[rA * DD + swz] = pA;
            } else if (grp == 1) {
                unsigned long long q = *(const unsigned long long*)&pbuf[rB * DD + (fq << 2)];
                unsigned int q0 = (unsigned int)q, q1 = (unsigned int)(q >> 32);
                b0 += __uint_as_float(q0 << 16);
                b1 += __uint_as_float(q0 & 0xffff0000u);
                b2 += __uint_as_float(q1 << 16);
                b3 += __uint_as_float(q1 & 0xffff0000u);
                float inv = 1.f / fmaxf((float)ctB, 1.f);
                b0 *= inv; b1 *= inv; b2 *= inv; b3 *= inv;
                unsigned long long pB =
                    (unsigned long long)((unsigned int)f2b(b0) | ((unsigned int)f2b(b1) << 16))
                    | ((unsigned long long)((unsigned int)f2b(b2) | ((unsigned int)f2b(b3) << 16)) << 32);
                int swz = (fq * 4) ^ ((rB & 7) << 3);
                *(unsigned long long*)&bk[rB * DD + swz] = pB;
            }
        }

        // ---- MFMA phase (A from bk means; B frags direct from L2-hot wsw) ----
        int arow = w * 16 + (lane & 15);
        int kb = (lane >> 4) * 8;
        int selfrow = base + arow; if (selfrow > NN - 1) selfrow = NN - 1;
        short8 am[2], ax[2];
#pragma unroll
        for (int ss = 0; ss < 2; ++ss) {
            int f0 = (kb + 32 * ss) ^ ((arow & 7) << 3);
            am[ss] = *(const short8*)&bk[arow * DD + f0];
            ax[ss] = *(const short8*)&xin[(gn0 + selfrow) * DD + kb + 32 * ss];
        }

        float4v acc[4];
#pragma unroll
        for (int c = 0; c < 4; ++c) {
            float b = bias[g * DD + c * 16 + (lane & 15)];
            acc[c] = {b, b, b, b};
        }
#pragma unroll
        for (int c = 0; c < 4; ++c) {
            int col = c * 16 + (lane & 15);
            int cswz = (col & 7) << 3;
#pragma unroll
            for (int ss = 0; ss < 2; ++ss) {
                short8 bl = *(const short8*)&wt[col * DD + ((kb + 32 * ss) ^ cswz)];
                acc[c] = __builtin_amdgcn_mfma_f32_16x16x32_bf16(am[ss], bl, acc[c], 0, 0, 0);
            }
#pragma unroll
            for (int ss = 0; ss < 2; ++ss) {
                short8 br = *(const short8*)&wt[DD * DD + col * DD + ((kb + 32 * ss) ^ cswz)];
                acc[c] = __builtin_amdgcn_mfma_f32_16x16x32_bf16(ax[ss], br, acc[c], 0, 0, 0);
            }
        }

        int q = lane >> 4, cl = lane & 15;
#pragma unroll
        for (int c = 0; c < 4; ++c) {
            int col = c * 16 + cl;
#pragma unroll
            for (int r = 0; r < 4; ++r) {
                int grow = base + w * 16 + q * 4 + r;
                if (grow >= NN) continue;
                float v = acc[c][r];
                v = v > 0.f ? v : expm1f(v);
                if (LAYER == 0)
                    ((unsigned short*)outp)[(gn0 + grow) * DD + col] = f2b(v);
                else
                    __builtin_nontemporal_store(v, &((float*)outp)[(gn0 + grow) * DD + col]);
            }
        }
    }
}

// ---- fallback (shfl-matvec, both sub-lists), runs only if probe failed -----
template <int LAYER>
__global__ void fallback_kernel(const unsigned short* __restrict__ xin,
                                const int* __restrict__ bcnt,
                                const unsigned int* __restrict__ part,
                                const float* __restrict__ Wl, const float* __restrict__ Wr,
                                const float* __restrict__ bias, void* __restrict__ outp,
                                const int* __restrict__ flags) {
    if (flags[0] & 2) return;
    __shared__ float sWl[DD * DD];
    __shared__ float sWr[DD * DD];
    __shared__ float sb[DD];
    __shared__ unsigned short bk[NT * CAP];
    __shared__ int cnt_lds[NT];

    int s = blockIdx.x & 7, tb = blockIdx.x >> 3;
    int g = s >> 1;
    int tile = (s & 1) * NTILE + tb;
    int base = tile * NT;
    long gn0 = (long)g * NN;

    if (threadIdx.x < NT) cnt_lds[threadIdx.x] = 0;
    for (int i = threadIdx.x; i < DD * DD; i += blockDim.x) {
        sWl[i] = Wl[(long)g * DD * DD + i];
        sWr[i] = Wr[(long)g * DD * DD + i];
    }
    if (threadIdx.x < DD) sb[threadIdx.x] = bias[g * DD + threadIdx.x];
    __syncthreads();

    for (int hf = 0; hf < 2; ++hf) {
        int pidx = (g * NTG + tile) * 2 + hf;
        int rc = bcnt[pidx * CPAD]; rc = rc < HCAP ? rc : HCAP;
        const unsigned int* reg = part + (long)pidx * HCAP;
        for (int i = threadIdx.x; i < rc; i += 256) {
            unsigned int p = reg[i];
            int dl = (p >> 16) & 63;
            int pos = atomicAdd(&cnt_lds[dl], 1);
            if (pos < CAP) bk[dl * CAP + pos] = (unsigned short)(p & 0xffffu);
        }
        __syncthreads();
    }

    int lane = threadIdx.x & 63;
    int w = threadIdx.x >> 6;
    for (int j = 0; j < 16; ++j) {
        int rl = w * 16 + j;
        int node = base + rl;
        if (node >= NN) continue;
        long row = gn0 + node;
        int ne = cnt_lds[rl];
        int nuse = ne < CAP ? ne : CAP;
        int msrc = (int)bk[rl * CAP + lane];
        float sum = 0.f;
        for (int e = 0; e < nuse; ++e) {
            int a0 = __shfl(msrc, e);
            sum += b2f(xin[(gn0 + a0) * DD + lane]);
        }
        float mean = sum / fmaxf((float)ne, 1.f);
        float self = b2f(xin[row * DD + lane]);
        float acc = sb[lane];
#pragma unroll
        for (int k = 0; k < DD; ++k) {
            float mk = __shfl(mean, k);
            float xk = __shfl(self, k);
            acc += mk * sWl[k * DD + lane] + xk * sWr[k * DD + lane];
        }
        acc = acc > 0.f ? acc : expm1f(acc);
        if (LAYER == 0) ((unsigned short*)outp)[row * DD + lane] = f2b(acc);
        else            ((float*)outp)[row * DD + lane] = acc;
    }
}

extern "C" void kernel_launch(void* const* d_in, const int* in_sizes, int n_in,
                              void* d_out, int out_size, void* d_ws, size_t ws_size,
                              hipStream_t stream) {
    const float* x   = (const float*)d_in[0];
    const int*   ei  = (const int*)d_in[1];
    const float* Wl1 = (const float*)d_in[2];
    const float* Wr1 = (const float*)d_in[3];
    const float* b1  = (const float*)d_in[4];
    const float* Wl2 = (const float*)d_in[5];
    const float* Wr2 = (const float*)d_in[6];
    const float* b2  = (const float*)d_in[7];
    float* out = (float*)d_out;

    // ws: part u32[4*782*2*768] (19.2MB) | bcnt i32[4*782*2*16] (400KB) |
    //     h u16[4*50000*64] (25.6MB) | wsw u16[2*4*2*4096] (128KB) | flags i32
    unsigned int* part = (unsigned int*)d_ws;
    int* bcnt = (int*)(part + (size_t)NG * NTG * 2 * HCAP);
    unsigned short* h = (unsigned short*)(bcnt + (size_t)NG * NTG * 2 * CPAD);
    unsigned short* wsw = h + (size_t)NG * NN * DD;
    int* flags = (int*)(wsw + (size_t)2 * NG * 2 * DD * DD);
    // xb (x as bf16, 25.6MB) lives in d_out's first half; dead before layer 2
    unsigned short* xb = (unsigned short*)d_out;

    hipMemsetAsync(bcnt, 0, (size_t)NG * NTG * 2 * CPAD * sizeof(int), stream);
    init_kernel<<<1, 64, 0, stream>>>(ei, flags);
    partition_kernel<<<PBLK * 8, 256, 0, stream>>>(ei, flags, bcnt, part);
    convert_kernel<<<2048, 256, 0, stream>>>(x, xb);
    wconv_kernel<<<8, 256, 0, stream>>>(Wl1, Wr1, Wl2, Wr2, wsw);

    const int sgrid = 2048;      // 8 blocks/CU x 256 CU = one dispatch wave
    const int fgrid = NTILE * 8;
    // layer 1: xb -> h (bf16)
    sage_mfma_kernel<0><<<sgrid, 256, 0, stream>>>(xb, bcnt, part, wsw, b1, h, flags);
    fallback_kernel<0><<<fgrid, 256, 0, stream>>>(xb, bcnt, part, Wl1, Wr1, b1, h, flags);
    // layer 2: h -> out (f32)
    sage_mfma_kernel<1><<<sgrid, 256, 0, stream>>>(h, bcnt, part, wsw, b2, out, flags);
    fallback_kernel<1><<<fgrid, 256, 0, stream>>>(h, bcnt, part, Wl2, Wr2, b2, out, flags);
}

// Round 16
// 261.396 us; speedup vs baseline: 1.5076x; 1.5076x over previous
//
#include <hip/hip_runtime.h>
#include <hip/hip_bf16.h>
#include <math.h>

#define NG 4
#define NN 50000
#define NE 800000
#define DD 64
#define CAP 64
#define NT 64             // nodes per block tile
#define NTILE 391         // tiles per (graph, half)
#define NTG (2 * NTILE)   // tiles (regions) per graph = 782
#define RCAP 1536         // region capacity (Poisson mean 1024, 16 sigma)
#define CPAD 16           // ints per region counter (one 64B line each)
#define PBLK 128          // partition blocks per slot (1024 total)
#define CHUNK (NE / PBLK) // 6250 edges per block
#define LBINS 392         // regions a slot can touch
#define BCAP 20           // LDS bin capacity (overflow path below)
#define SBLK 192          // sage blocks per slot: 1536 total = 6/CU, all resident

typedef __attribute__((ext_vector_type(8))) short short8;
typedef __attribute__((ext_vector_type(4))) float float4v;

__device__ __forceinline__ unsigned short f2b(float f) {
    union { __hip_bfloat16 h; unsigned short u; } cv;
    cv.h = __float2bfloat16(f);
    return cv.u;
}
__device__ __forceinline__ float b2f(unsigned short u) {
    union { unsigned short u; __hip_bfloat16 h; } cv;
    cv.u = u;
    return __bfloat162float(cv.h);
}

// ---- init: detect int64 (bit0) + verify MFMA layout (bit1), one block ------
__global__ void init_kernel(const int* __restrict__ ei, int* __restrict__ flags) {
    __shared__ alignas(16) unsigned short A[16 * 32];
    __shared__ unsigned short B[32 * 16];
    int t = threadIdx.x;
    int any_nonzero = 0;
    for (int i = t; i < 128; i += 64) any_nonzero |= ei[2 * i + 1];
    unsigned long long nz = __ballot(any_nonzero != 0);
    int is64 = (nz == 0ULL) ? 1 : 0;
    for (int i = t; i < 512; i += 64) {
        int r = i >> 5, k = i & 31;
        A[i] = f2b((float)(((r * 5 + k * 3) & 31) - 15));
        int kk = i >> 4, c = i & 15;
        B[i] = f2b((float)(((kk * 7 + c * 11) & 31) - 15));
    }
    __syncthreads();
    short8 a = *(const short8*)&A[(t & 15) * 32 + (t >> 4) * 8];
    int c = t & 15, kb = (t >> 4) * 8;
    short8 b;
    for (int j = 0; j < 8; ++j) b[j] = (short)B[(kb + j) * 16 + c];
    float4v acc = {0.f, 0.f, 0.f, 0.f};
    acc = __builtin_amdgcn_mfma_f32_16x16x32_bf16(a, b, acc, 0, 0, 0);
    int ok = 1;
    for (int reg = 0; reg < 4; ++reg) {
        int row = (t >> 4) * 4 + reg;
        float ref = 0.f;
        for (int k = 0; k < 32; ++k)
            ref += (float)(((row * 5 + k * 3) & 31) - 15) *
                   (float)(((k * 7 + c * 11) & 31) - 15);
        if (acc[reg] != ref) ok = 0;
    }
    unsigned long long vote = __ballot(ok);
    if (t == 0) flags[0] = is64 | ((vote == ~0ULL) ? 2 : 0);
}

// nt (streaming) edge-index load
__device__ __forceinline__ int nt_idx(const int* __restrict__ ei, long pos, int is64) {
    return is64 ? __builtin_nontemporal_load(ei + 2 * pos)
                : __builtin_nontemporal_load(ei + pos);
}

// ---- partition via LDS-staged aggregation (proven round 10) ----------------
__global__ void partition_kernel(const int* __restrict__ ei, const int* __restrict__ flags,
                                 int* __restrict__ bcnt, unsigned int* __restrict__ part) {
    __shared__ int lcnt[LBINS];
    __shared__ int basev[LBINS];
    __shared__ unsigned int lbuf[LBINS * BCAP];

    int is64 = flags[0] & 1;
    int s = blockIdx.x & 7;
    int g = s >> 1;
    int lo = (s & 1) * (NN / 2), hi = lo + (NN / 2);
    int rbase0 = lo >> 6;
    int bsl = blockIdx.x >> 3;
    int e0 = bsl * CHUNK, e1 = e0 + CHUNK;
    long ebase = (long)g * 2 * NE;

    for (int i = threadIdx.x; i < LBINS; i += 256) lcnt[i] = 0;
    __syncthreads();

    for (int e = e0 + threadIdx.x; e < e1; e += 256) {
        int d = nt_idx(ei, ebase + NE + e, is64);
        int sc = nt_idx(ei, ebase + e, is64);
        if (d >= lo && d < hi) {
            int lb = (d >> 6) - rbase0;
            unsigned int pk = ((unsigned int)d << 16) | (unsigned int)(sc & 0xffff);
            int pos = atomicAdd(&lcnt[lb], 1);
            if (pos < BCAP) {
                lbuf[lb * BCAP + pos] = pk;
            } else {
                int gp = atomicAdd(&bcnt[(g * NTG + (d >> 6)) * CPAD], 1);
                if (gp < RCAP) part[(long)(g * NTG + (d >> 6)) * RCAP + gp] = pk;
            }
        }
    }
    __syncthreads();

    for (int r = threadIdx.x; r < LBINS; r += 256) {
        int c = lcnt[r]; c = c < BCAP ? c : BCAP;
        basev[r] = c ? atomicAdd(&bcnt[(g * NTG + rbase0 + r) * CPAD], c) : 0;
    }
    __syncthreads();

    int w = threadIdx.x >> 6, hw = (threadIdx.x >> 5) & 1, l32 = threadIdx.x & 31;
    for (int r = w * 2 + hw; r < LBINS; r += 8) {
        int c = lcnt[r]; c = c < BCAP ? c : BCAP;
        int b = basev[r];
        if (l32 < c && b + l32 < RCAP)
            part[(long)(g * NTG + rbase0 + r) * RCAP + b + l32] = lbuf[r * BCAP + l32];
    }
}

// ---- convert x f32 -> bf16 -------------------------------------------------
__global__ void convert_kernel(const float* __restrict__ x, unsigned short* __restrict__ xb) {
    long total = (long)NG * NN * DD / 4;
    long stride = (long)gridDim.x * blockDim.x;
    const float4* src = (const float4*)x;
    unsigned long long* dst = (unsigned long long*)xb;
    for (long i = (long)blockIdx.x * blockDim.x + threadIdx.x; i < total; i += stride) {
        float4 v = src[i];
        unsigned long long p = (unsigned long long)f2b(v.x)
                             | ((unsigned long long)f2b(v.y) << 16)
                             | ((unsigned long long)f2b(v.z) << 32)
                             | ((unsigned long long)f2b(v.w) << 48);
        dst[i] = p;
    }
}

// ---- wconv: precompute bf16-swizzled W^T for both layers (once) ------------
__global__ void wconv_kernel(const float* __restrict__ Wl1, const float* __restrict__ Wr1,
                             const float* __restrict__ Wl2, const float* __restrict__ Wr2,
                             unsigned short* __restrict__ wsw) {
    int g = blockIdx.x & 3, layer = blockIdx.x >> 2;
    const float* Wl = layer ? Wl2 : Wl1;
    const float* Wr = layer ? Wr2 : Wr1;
    for (int i = threadIdx.x; i < 2 * DD * DD; i += 256) {
        int m = i >> 12, rem = i & 4095, k = rem >> 6, col = rem & 63;
        float wv = (m == 0 ? Wl : Wr)[(long)g * DD * DD + rem];
        wsw[(((long)layer * NG + g) * 2 + m) * DD * DD + col * DD + (k ^ ((col & 7) << 3))]
            = f2b(wv);
    }
}

// ---- fused bin + gather + MFMA layer (r12 structure, persistent blocks) -----
// ROUND-16: restore r12 (proven best: 106us/layer, 6 blocks/CU = the
// locality-optimal concurrency per r13/r15 thrash evidence) with ONE change:
// 1536 persistent blocks (exactly 6/CU) grid-striding over tiles. Removes the
// 2.04-dispatch-wave tail drain (r12's time-avg occupancy was 47% vs 75%
// static) and amortizes sWT staging once per block instead of per tile.
// Per-XCD concurrency unchanged -> no thrash regression possible.
template <int LAYER>  // 0: out = h (bf16), 1: out = d_out (f32)
__launch_bounds__(256, 6)
__global__ void sage_mfma_kernel(const unsigned short* __restrict__ xin,
                                 const int* __restrict__ bcnt,
                                 const unsigned int* __restrict__ part,
                                 const unsigned short* __restrict__ wsw,
                                 const float* __restrict__ bias, void* __restrict__ outp,
                                 const int* __restrict__ flags) {
    if (!(flags[0] & 2)) return;
    __shared__ alignas(16) unsigned short sWT[2 * DD * DD];  // 16KB
    __shared__ alignas(16) unsigned short sM[NT * DD];       // bucket, then means, 8KB
    __shared__ int cnt_lds[NT];

    int s = blockIdx.x & 7;
    int bsl = blockIdx.x >> 3, nbsl = gridDim.x >> 3;
    int g = s >> 1;
    long gn0 = (long)g * NN;

    // stage precomputed W^T once per block (16KB, b128 copy)
    {
        const short8* wsrc = (const short8*)(wsw + ((long)LAYER * NG + g) * 2 * DD * DD);
        short8* wdst = (short8*)sWT;
        for (int i = threadIdx.x; i < 1024; i += 256) wdst[i] = wsrc[i];
    }

    int lane = threadIdx.x & 63;
    int w = threadIdx.x >> 6;
    int grp = lane >> 4;       // edge slot 0..3
    int fq  = lane & 15;       // feature quad: features 4fq..4fq+3
    const char* xg = (const char*)xin + (gn0 << 7);  // graph row base (128B rows)

    for (int tb = bsl; tb < NTILE; tb += nbsl) {
        int tile = (s & 1) * NTILE + tb;
        int base = tile * NT;

        __syncthreads();   // protect sM/cnt reuse (and sWT visibility, 1st iter)
        if (threadIdx.x < NT) cnt_lds[threadIdx.x] = 0;
        __syncthreads();

        // ---- bin this tile's region into LDS (nt stream) ----
        int rc = bcnt[(g * NTG + tile) * CPAD];
        int rcount = rc < RCAP ? rc : RCAP;
        const unsigned int* reg = part + (long)(g * NTG + tile) * RCAP;
        for (int i = threadIdx.x; i < rcount; i += 256) {
            unsigned int p = __builtin_nontemporal_load(reg + i);
            int dl = (p >> 16) & 63;
            int pos = atomicAdd(&cnt_lds[dl], 1);
            if (pos < CAP) sM[dl * DD + pos] = (unsigned short)(p & 0xffffu);
        }
        __syncthreads();

        // ---- gather phase: 2 rows x 4 edges per iteration (r12 proven) ----
#pragma unroll 1
        for (int j = 0; j < 8; ++j) {
            int rA = w * 16 + j, rB = rA + 8;
            int neA = cnt_lds[rA], neB = cnt_lds[rB];
            int nuA = neA < CAP ? neA : CAP; if (base + rA >= NN) nuA = 0;
            int nuB = neB < CAP ? neB : CAP; if (base + rB >= NN) nuB = 0;
            int msA = (int)sM[rA * DD + lane];
            int msB = (int)sM[rB * DD + lane];
            float a0 = 0.f, a1 = 0.f, a2 = 0.f, a3 = 0.f;
            float b0 = 0.f, b1 = 0.f, b2 = 0.f, b3 = 0.f;
            int numax = nuA > nuB ? nuA : nuB;
#pragma unroll 4
            for (int e = 0; e < numax; e += 4) {
                int ei = e + grp;
                bool vA = ei < nuA, vB = ei < nuB;
                int sA = __shfl(msA, vA ? ei : 0);
                int sB = __shfl(msB, vB ? ei : 0);
                sA = sA < NN - 1 ? sA : NN - 1;
                sB = sB < NN - 1 ? sB : NN - 1;
                unsigned long long va =
                    *(const unsigned long long*)(xg + ((long)sA << 7) + (fq << 3));
                unsigned long long vb =
                    *(const unsigned long long*)(xg + ((long)sB << 7) + (fq << 3));
                unsigned int ua0 = (unsigned int)va, ua1 = (unsigned int)(va >> 32);
                unsigned int ub0 = (unsigned int)vb, ub1 = (unsigned int)(vb >> 32);
                if (!vA) { ua0 = 0u; ua1 = 0u; }
                if (!vB) { ub0 = 0u; ub1 = 0u; }
                a0 += __uint_as_float(ua0 << 16);
                a1 += __uint_as_float(ua0 & 0xffff0000u);
                a2 += __uint_as_float(ua1 << 16);
                a3 += __uint_as_float(ua1 & 0xffff0000u);
                b0 += __uint_as_float(ub0 << 16);
                b1 += __uint_as_float(ub0 & 0xffff0000u);
                b2 += __uint_as_float(ub1 << 16);
                b3 += __uint_as_float(ub1 & 0xffff0000u);
            }
            a0 += __shfl_xor(a0, 16); a0 += __shfl_xor(a0, 32);
            a1 += __shfl_xor(a1, 16); a1 += __shfl_xor(a1, 32);
            a2 += __shfl_xor(a2, 16); a2 += __shfl_xor(a2, 32);
            a3 += __shfl_xor(a3, 16); a3 += __shfl_xor(a3, 32);
            b0 += __shfl_xor(b0, 16); b0 += __shfl_xor(b0, 32);
            b1 += __shfl_xor(b1, 16); b1 += __shfl_xor(b1, 32);
            b2 += __shfl_xor(b2, 16); b2 += __shfl_xor(b2, 32);
            b3 += __shfl_xor(b3, 16); b3 += __shfl_xor(b3, 32);
            float invA = 1.f / fmaxf((float)neA, 1.f);
            float invB = 1.f / fmaxf((float)neB, 1.f);
            a0 *= invA; a1 *= invA; a2 *= invA; a3 *= invA;
            b0 *= invB; b1 *= invB; b2 *= invB; b3 *= invB;
            unsigned long long pA =
                (unsigned long long)((unsigned int)f2b(a0) | ((unsigned int)f2b(a1) << 16))
                | ((unsigned long long)((unsigned int)f2b(a2) | ((unsigned int)f2b(a3) << 16)) << 32);
            unsigned long long pB =
                (unsigned long long)((unsigned int)f2b(b0) | ((unsigned int)f2b(b1) << 16))
                | ((unsigned long long)((unsigned int)f2b(b2) | ((unsigned int)f2b(b3) << 16)) << 32);
            if (grp == 0) {
                int swz = (fq * 4) ^ ((rA & 7) << 3);
                *(unsigned long long*)&sM[rA * DD + swz] = pA;
            } else if (grp == 1) {
                int swz = (fq * 4) ^ ((rB & 7) << 3);
                *(unsigned long long*)&sM[rB * DD + swz] = pB;
            }
        }

        // ---- MFMA phase (A-frags from own-wave sM; B frags from LDS sWT) ----
        int arow = w * 16 + (lane & 15);
        int kb = (lane >> 4) * 8;
        int selfrow = base + arow; if (selfrow > NN - 1) selfrow = NN - 1;
        short8 am[2], ax[2];
#pragma unroll
        for (int ss = 0; ss < 2; ++ss) {
            int f0 = (kb + 32 * ss) ^ ((arow & 7) << 3);
            am[ss] = *(const short8*)&sM[arow * DD + f0];
            ax[ss] = *(const short8*)&xin[(gn0 + selfrow) * DD + kb + 32 * ss];
        }

        float4v acc[4];
#pragma unroll
        for (int c = 0; c < 4; ++c) {
            float b = bias[g * DD + c * 16 + (lane & 15)];
            acc[c] = {b, b, b, b};
        }
#pragma unroll
        for (int c = 0; c < 4; ++c) {
            int col = c * 16 + (lane & 15);
            int cswz = (col & 7) << 3;
#pragma unroll
            for (int ss = 0; ss < 2; ++ss) {
                short8 bl = *(const short8*)&sWT[0 * DD * DD + col * DD + ((kb + 32 * ss) ^ cswz)];
                acc[c] = __builtin_amdgcn_mfma_f32_16x16x32_bf16(am[ss], bl, acc[c], 0, 0, 0);
            }
#pragma unroll
            for (int ss = 0; ss < 2; ++ss) {
                short8 br = *(const short8*)&sWT[1 * DD * DD + col * DD + ((kb + 32 * ss) ^ cswz)];
                acc[c] = __builtin_amdgcn_mfma_f32_16x16x32_bf16(ax[ss], br, acc[c], 0, 0, 0);
            }
        }

        int q = lane >> 4, cl = lane & 15;
#pragma unroll
        for (int c = 0; c < 4; ++c) {
            int col = c * 16 + cl;
#pragma unroll
            for (int r = 0; r < 4; ++r) {
                int grow = base + w * 16 + q * 4 + r;
                if (grow >= NN) continue;
                float v = acc[c][r];
                v = v > 0.f ? v : expm1f(v);
                if (LAYER == 0)
                    ((unsigned short*)outp)[(gn0 + grow) * DD + col] = f2b(v);
                else  // final output: never re-read -> nt store keeps h in L2
                    __builtin_nontemporal_store(v, &((float*)outp)[(gn0 + grow) * DD + col]);
            }
        }
    }
}

// ---- fallback (shfl-matvec on binned tile), runs only if probe failed ------
template <int LAYER>
__global__ void fallback_kernel(const unsigned short* __restrict__ xin,
                                const int* __restrict__ bcnt,
                                const unsigned int* __restrict__ part,
                                const float* __restrict__ Wl, const float* __restrict__ Wr,
                                const float* __restrict__ bias, void* __restrict__ outp,
                                const int* __restrict__ flags) {
    if (flags[0] & 2) return;
    __shared__ float sWl[DD * DD];
    __shared__ float sWr[DD * DD];
    __shared__ float sb[DD];
    __shared__ unsigned short bk[NT * CAP];
    __shared__ int cnt_lds[NT];

    int s = blockIdx.x & 7, tb = blockIdx.x >> 3;
    int g = s >> 1;
    int tile = (s & 1) * NTILE + tb;
    int base = tile * NT;
    long gn0 = (long)g * NN;

    if (threadIdx.x < NT) cnt_lds[threadIdx.x] = 0;
    for (int i = threadIdx.x; i < DD * DD; i += blockDim.x) {
        sWl[i] = Wl[(long)g * DD * DD + i];
        sWr[i] = Wr[(long)g * DD * DD + i];
    }
    if (threadIdx.x < DD) sb[threadIdx.x] = bias[g * DD + threadIdx.x];
    __syncthreads();

    int rc = bcnt[(g * NTG + tile) * CPAD];
    int rcount = rc < RCAP ? rc : RCAP;
    const unsigned int* reg = part + (long)(g * NTG + tile) * RCAP;
    for (int i = threadIdx.x; i < rcount; i += 256) {
        unsigned int p = reg[i];
        int dl = (p >> 16) & 63;
        int pos = atomicAdd(&cnt_lds[dl], 1);
        if (pos < CAP) bk[dl * CAP + pos] = (unsigned short)(p & 0xffffu);
    }
    __syncthreads();

    int lane = threadIdx.x & 63;
    int w = threadIdx.x >> 6;
    for (int j = 0; j < 16; ++j) {
        int rl = w * 16 + j;
        int node = base + rl;
        if (node >= NN) continue;
        long row = gn0 + node;
        int ne = cnt_lds[rl];
        int nuse = ne < CAP ? ne : CAP;
        int msrc = (int)bk[rl * CAP + lane];
        float sum = 0.f;
        for (int e = 0; e < nuse; ++e) {
            int a0 = __shfl(msrc, e);
            sum += b2f(xin[(gn0 + a0) * DD + lane]);
        }
        float mean = sum / fmaxf((float)ne, 1.f);
        float self = b2f(xin[row * DD + lane]);
        float acc = sb[lane];
#pragma unroll
        for (int k = 0; k < DD; ++k) {
            float mk = __shfl(mean, k);
            float xk = __shfl(self, k);
            acc += mk * sWl[k * DD + lane] + xk * sWr[k * DD + lane];
        }
        acc = acc > 0.f ? acc : expm1f(acc);
        if (LAYER == 0) ((unsigned short*)outp)[row * DD + lane] = f2b(acc);
        else            ((float*)outp)[row * DD + lane] = acc;
    }
}

extern "C" void kernel_launch(void* const* d_in, const int* in_sizes, int n_in,
                              void* d_out, int out_size, void* d_ws, size_t ws_size,
                              hipStream_t stream) {
    const float* x   = (const float*)d_in[0];
    const int*   ei  = (const int*)d_in[1];
    const float* Wl1 = (const float*)d_in[2];
    const float* Wr1 = (const float*)d_in[3];
    const float* b1  = (const float*)d_in[4];
    const float* Wl2 = (const float*)d_in[5];
    const float* Wr2 = (const float*)d_in[6];
    const float* b2  = (const float*)d_in[7];
    float* out = (float*)d_out;

    // ws: part u32[4*782*1536] (19.2MB) | bcnt i32[4*782*16] (200KB) |
    //     h u16[4*50000*64] (25.6MB) | wsw u16[2*4*2*4096] (128KB) | flags i32
    //     -> ~45.2MB, under the 52MB proven budget
    unsigned int* part = (unsigned int*)d_ws;
    int* bcnt = (int*)(part + (size_t)NG * NTG * RCAP);
    unsigned short* h = (unsigned short*)(bcnt + (size_t)NG * NTG * CPAD);
    unsigned short* wsw = h + (size_t)NG * NN * DD;
    int* flags = (int*)(wsw + (size_t)2 * NG * 2 * DD * DD);
    // xb (x as bf16, 25.6MB) lives in d_out's first half; dead before layer 2
    unsigned short* xb = (unsigned short*)d_out;

    hipMemsetAsync(bcnt, 0, (size_t)NG * NTG * CPAD * sizeof(int), stream);
    init_kernel<<<1, 64, 0, stream>>>(ei, flags);
    partition_kernel<<<PBLK * 8, 256, 0, stream>>>(ei, flags, bcnt, part);
    convert_kernel<<<2048, 256, 0, stream>>>(x, xb);
    wconv_kernel<<<8, 256, 0, stream>>>(Wl1, Wr1, Wl2, Wr2, wsw);

    const int sgrid = SBLK * 8;  // 1536 persistent blocks = 6/CU, all resident
    const int fgrid = NTILE * 8;
    // layer 1: xb -> h (bf16)
    sage_mfma_kernel<0><<<sgrid, 256, 0, stream>>>(xb, bcnt, part, wsw, b1, h, flags);
    fallback_kernel<0><<<fgrid, 256, 0, stream>>>(xb, bcnt, part, Wl1, Wr1, b1, h, flags);
    // layer 2: h -> out (f32)
    sage_mfma_kernel<1><<<sgrid, 256, 0, stream>>>(h, bcnt, part, wsw, b2, out, flags);
    fallback_kernel<1><<<fgrid, 256, 0, stream>>>(h, bcnt, part, Wl2, Wr2, b2, out, flags);
}